// Round 14
// baseline (142.025 us; speedup 1.0000x reference)
//
#include <hip/hip_runtime.h>
#include <cmath>

// ---------------------------------------------------------------------------
// Problem constants (from reference)
// ---------------------------------------------------------------------------
constexpr int kNsh    = 9;      // (LMAX+1)^2, LMAX=2
constexpr int kF      = 64;
constexpr int kNrbf   = 20;
constexpr int kNAtoms = 1000;
constexpr int kNPairs = 10000;
constexpr float kCutoffF = 5.0f;
constexpr int kMaxNZ  = 200;
constexpr int kCp     = 12;         // channel dim padded (9 -> 12) for b128
constexpr int kXs     = kF * kCp;   // 768 floats per atom, internal layout

// ---------------------------------------------------------------------------
// Compile-time real Clebsch-Gordan table (mirrors the reference _real_cg)
// ---------------------------------------------------------------------------
struct CGSparse {
  int n;
  int c[kMaxNZ];
  int a[kMaxNZ];
  int b[kMaxNZ];
  float v[kMaxNZ];
};

constexpr double cfact(int n) {
  double r = 1.0;
  for (int i = 2; i <= n; i++) r *= (double)i;
  return r;
}
constexpr double cabs_(double x) { return x < 0 ? -x : x; }
constexpr double csqrt_(double x) {
  if (x <= 0.0) return 0.0;
  double g = x < 1.0 ? 1.0 : x;
  for (int i = 0; i < 60; i++) g = 0.5 * (g + x / g);
  return g;
}

constexpr double cg_cplx(int l1, int m1, int l2, int m2, int l3, int m3) {
  if (m3 != m1 + m2) return 0.0;
  int lo = l1 > l2 ? l1 - l2 : l2 - l1;
  if (l3 < lo || l3 > l1 + l2) return 0.0;
  double pre = csqrt_((2 * l3 + 1) * cfact(l3 + l1 - l2) * cfact(l3 - l1 + l2) *
                      cfact(l1 + l2 - l3) / cfact(l1 + l2 + l3 + 1));
  pre *= csqrt_(cfact(l3 + m3) * cfact(l3 - m3) * cfact(l1 - m1) *
                cfact(l1 + m1) * cfact(l2 - m2) * cfact(l2 + m2));
  double s = 0.0;
  for (int k = 0; k <= l1 + l2 - l3; k++) {
    int d0 = k, d1 = l1 + l2 - l3 - k, d2 = l1 - m1 - k;
    int d3 = l2 + m2 - k, d4 = l3 - l2 + m1 + k, d5 = l3 - l1 - m2 + k;
    if (d0 < 0 || d1 < 0 || d2 < 0 || d3 < 0 || d4 < 0 || d5 < 0) continue;
    double den = cfact(d0) * cfact(d1) * cfact(d2) * cfact(d3) * cfact(d4) * cfact(d5);
    s += ((k % 2) ? -1.0 : 1.0) / den;
  }
  return pre * s;
}

constexpr CGSparse build_cg() {
  CGSparse out{};
  int lidx[9] = {0, 1, 1, 1, 2, 2, 2, 2, 2};
  int midx[9] = {0, -1, 0, 1, -2, -1, 0, 1, 2};
  double Ur[9][9] = {};
  double Ui[9][9] = {};
  for (int l = 0; l <= 2; l++) {
    int base = l * l + l;
    Ur[base][base] = 1.0;
    for (int m = 1; m <= l; m++) {
      double s2 = 1.0 / csqrt_(2.0);
      double sgn = (m % 2) ? -1.0 : 1.0;
      Ur[base + m][base - m] = s2;
      Ur[base + m][base + m] = sgn * s2;
      Ui[base - m][base - m] = s2;
      Ui[base - m][base + m] = -sgn * s2;
    }
  }
  double cgr[9][9][9] = {};
  for (int i = 0; i < 9; i++)
    for (int j = 0; j < 9; j++)
      for (int k = 0; k < 9; k++) {
        double cv = cg_cplx(lidx[i], midx[i], lidx[j], midx[j], lidx[k], midx[k]);
        if (cv == 0.0) continue;
        for (int a2 = 0; a2 < 9; a2++) {
          if (Ur[a2][i] == 0.0 && Ui[a2][i] == 0.0) continue;
          for (int b2 = 0; b2 < 9; b2++) {
            if (Ur[b2][j] == 0.0 && Ui[b2][j] == 0.0) continue;
            for (int c2 = 0; c2 < 9; c2++) {
              if (Ur[c2][k] == 0.0 && Ui[c2][k] == 0.0) continue;
              double ar = Ur[a2][i], ai = Ui[a2][i];
              double br = Ur[b2][j], bi = Ui[b2][j];
              double cr = Ur[c2][k], ci = -Ui[c2][k];  // conj
              double pr = ar * br - ai * bi;
              double pi = ar * bi + ai * br;
              double rr = pr * cr - pi * ci;  // real part
              cgr[c2][a2][b2] += rr * cv;
            }
          }
        }
      }
  int n = 0;
  for (int c2 = 0; c2 < 9; c2++)
    for (int a2 = 0; a2 < 9; a2++)
      for (int b2 = 0; b2 < 9; b2++) {
        bool mask = ((lidx[a2] + lidx[b2]) % 2) == (lidx[c2] % 2);
        double v = mask ? cgr[c2][a2][b2] : 0.0;
        if (cabs_(v) > 1e-9) {
          out.c[n] = c2;
          out.a[n] = a2;
          out.b[n] = b2;
          out.v[n] = (float)v;
          n++;
        }
      }
  out.n = n;
  return out;
}

constexpr CGSparse CG = build_cg();
static_assert(CG.n > 0 && CG.n <= kMaxNZ, "CG table size out of range");

// ---------------------------------------------------------------------------
// k_pre: pair geometry + radial filters (both t) | segment offsets
// ---------------------------------------------------------------------------
constexpr int kPreBlkPairs = kNPairs / 4;                 // 2500
constexpr int kPreBlkSeg   = (kNAtoms + 1 + 255) / 256;   // 4
constexpr int kPreBlkTotal = kPreBlkPairs + kPreBlkSeg;

__global__ __launch_bounds__(256) void k_pre(
    const float* __restrict__ rij, const float* __restrict__ Wf,
    const float* __restrict__ bf, const int* __restrict__ idx_i,
    float* __restrict__ Ypd, float* __restrict__ Wpair,
    int* __restrict__ seg) {
  const int blk = blockIdx.x;
  if (blk < kPreBlkPairs) {
    int wv = threadIdx.x >> 6;
    int f = threadIdx.x & 63;
    int p = blk * 4 + wv;
    float rx = rij[3 * p + 0], ry = rij[3 * p + 1], rz = rij[3 * p + 2];
    float d = sqrtf(rx * rx + ry * ry + rz * rz);
    float inv = 1.0f / d;
    float x = rx * inv, y = ry * inv, z = rz * inv;
    const float c0 = 0.28209479177387814f;  // 0.5/sqrt(pi)
    const float c1 = 0.4886025119029199f;   // sqrt(3/(4pi))
    const float c2 = 1.0925484305920792f;   // 0.5*sqrt(15/pi)
    const float c3 = 0.31539156525252005f;  // 0.25*sqrt(5/pi)
    const float c4 = 0.5462742152960396f;   // 0.25*sqrt(15/pi)
    if (f < 9) {
      float yv =
          (f == 0) ? c0 :
          (f == 1) ? c1 * y :
          (f == 2) ? c1 * z :
          (f == 3) ? c1 * x :
          (f == 4) ? c2 * x * y :
          (f == 5) ? c2 * y * z :
          (f == 6) ? c3 * (3.0f * z * z - 1.0f) :
          (f == 7) ? c2 * x * z :
                     c4 * (x * x - y * y);
      Ypd[p * 16 + f] = yv;
    }
    float cut = (d < kCutoffF) ? 0.5f * (cosf(d * (float)(M_PI / 5.0)) + 1.0f) : 0.0f;
    float radial[kNrbf];
    const float width = kCutoffF / (kNrbf - 1);
    const float coef = -0.5f / (width * width);
    #pragma unroll
    for (int k = 0; k < kNrbf; k++) {
      float off = (kCutoffF * k) / (kNrbf - 1);
      float tt = d - off;
      radial[k] = expf(coef * tt * tt);
    }
    #pragma unroll
    for (int t = 0; t < 2; t++) {
      #pragma unroll
      for (int l = 0; l < 3; l++) {
        float w = bf[t * 192 + l * 64 + f];
        #pragma unroll
        for (int k = 0; k < kNrbf; k++) {
          w += radial[k] * Wf[t * (kNrbf * 192) + k * 192 + l * 64 + f];
        }
        Wpair[t * (kNPairs * 192) + p * 192 + l * 64 + f] = w * cut;
      }
    }
  } else {
    int a = (blk - kPreBlkPairs) * 256 + threadIdx.x;
    if (a <= kNAtoms) {
      int lo = 0, hi = kNPairs;
      while (lo < hi) {
        int mid = (lo + hi) >> 1;
        if (idx_i[mid] < a) lo = mid + 1; else hi = mid;
      }
      seg[a] = lo;
    }
  }
}

// ---------------------------------------------------------------------------
// Helpers
// ---------------------------------------------------------------------------
// k-split matmul partial: wave covers 16 k-slices of the 12c x 64f tile.
// W streamed from global (L2-broadcast) in two 8-slice register stages.
__device__ __forceinline__ void mm_phase(const float* __restrict__ sIn,
                                         const float* __restrict__ W,
                                         float* __restrict__ sRw,
                                         int k0, int cgi, int fb) {
  if (cgi >= 3) return;
  const int c0 = cgi * 4;
  float acc[4][4];
  #pragma unroll
  for (int i = 0; i < 4; i++)
    #pragma unroll
    for (int j = 0; j < 4; j++) acc[i][j] = 0.f;
  #pragma unroll
  for (int half = 0; half < 2; half++) {
    float4 wr[8];
    #pragma unroll
    for (int kk = 0; kk < 8; kk++) {
      wr[kk] = *(const float4*)(W + (k0 + half * 8 + kk) * kF + fb);
    }
    #pragma unroll
    for (int kk = 0; kk < 8; kk++) {
      int k = k0 + half * 8 + kk;
      float4 av = *(const float4*)(sIn + k * kCp + c0);
      float4 wv = wr[kk];
      float a[4] = {av.x, av.y, av.z, av.w};
      float w[4] = {wv.x, wv.y, wv.z, wv.w};
      #pragma unroll
      for (int i = 0; i < 4; i++)
        #pragma unroll
        for (int j = 0; j < 4; j++) acc[i][j] += a[i] * w[j];
    }
  }
  #pragma unroll
  for (int j = 0; j < 4; j++) {
    float4 v = {acc[0][j], acc[1][j], acc[2][j], acc[3][j]};
    *(float4*)(sRw + (fb + j) * kCp + c0) = v;
  }
}

// per-lane sum of the 4 wave partials at this lane's row -> out12 (registers)
__device__ __forceinline__ void sum4(const float (*sR)[kF * kCp], int lane,
                                     float* __restrict__ out12) {
  const float4* r0 = (const float4*)(sR[0] + lane * kCp);
  const float4* r1 = (const float4*)(sR[1] + lane * kCp);
  const float4* r2 = (const float4*)(sR[2] + lane * kCp);
  const float4* r3 = (const float4*)(sR[3] + lane * kCp);
  #pragma unroll
  for (int q = 0; q < 3; q++) {
    float4 a = r0[q], b = r1[q], c = r2[q], d = r3[q];
    float4 s = {a.x + b.x + c.x + d.x, a.y + b.y + c.y + d.y,
                a.z + b.z + c.z + d.z, a.w + b.w + c.w + d.w};
    *(float4*)(out12 + 4 * q) = s;
  }
}

// store 12 floats to row `lane` of an f-major staging buffer
__device__ __forceinline__ void st12(float* __restrict__ dst, int lane,
                                     const float* __restrict__ v) {
  float4* d4 = (float4*)(dst + lane * kCp);
  d4[0] = *(const float4*)(v + 0);
  d4[1] = *(const float4*)(v + 4);
  d4[2] = *(const float4*)(v + 8);
}

// ---------------------------------------------------------------------------
// k_inter<T>: fused message + update, one block (4 waves) per atom.
// Wave-redundant reduces: after each barrier, EVERY wave sums the 4 partials
// and writes the staging buffer (bit-identical values -> concurrent writes
// benign; each wave's 64 lanes cover all 64 rows, so a wave may read what it
// just wrote with no barrier). 4 barriers total (was 9).
// T==0: gather emb[Z[j]] (x0 virtual), write internal [f][12].
// T==1: gather x1, write standard [c][f] to out.
// ---------------------------------------------------------------------------
template <int T>
__global__ __launch_bounds__(256) void k_inter(
    const float* __restrict__ Ypd, const float* __restrict__ Wpt,
    const int* __restrict__ seg, const int* __restrict__ idx_j,
    const int* __restrict__ Z, const float* __restrict__ emb,
    const float* __restrict__ x_in, const float* __restrict__ W1,
    const float* __restrict__ W2, const float* __restrict__ W3,
    const float* __restrict__ Wg, const float* __restrict__ bg,
    float* __restrict__ x_out) {
  const int atom = blockIdx.x;
  const int tid = threadIdx.x;
  const int wv = tid >> 6;          // wave 0..3
  const int lane = tid & 63;
  const int cgi = lane >> 4;        // 0..3 (3 idle in mm)
  const int fb = (lane & 15) * 4;
  const int k0 = wv * 16;           // k-range for this wave

  __shared__ __align__(16) float sA[kF * kCp];     // 3 KB staging (dx/t2/dx2)
  __shared__ __align__(16) float sB[kF * kCp];     // 3 KB staging (dx3)
  __shared__ __align__(16) float sR[4][kF * kCp];  // 12 KB per-wave partials

  // ---- message + aggregation (pairs split across 4 waves) -> sR[wv] ----
  {
    float y[12];
    #pragma unroll
    for (int c = 0; c < 12; c++) y[c] = 0.f;
    const int s0 = seg[atom], s1 = seg[atom + 1];
    for (int p0 = s0 + wv; p0 < s1; p0 += 4) {
      const int p = __builtin_amdgcn_readfirstlane(p0);
      const int j = __builtin_amdgcn_readfirstlane(idx_j[p]);
      const float* Wp = Wpt + p * 192;
      float Wl0 = Wp[lane], Wl1 = Wp[64 + lane], Wl2 = Wp[128 + lane];
      const float* Yp = Ypd + p * 16;
      float YW[9];
      YW[0] = Yp[0] * Wl0;
      YW[1] = Yp[1] * Wl1;
      YW[2] = Yp[2] * Wl1;
      YW[3] = Yp[3] * Wl1;
      #pragma unroll
      for (int b = 4; b < 9; b++) YW[b] = Yp[b] * Wl2;
      if (T == 0) {
        // x[j] = emb[Z[j]] in channel 0 only: CG folds to a==0 entries
        float e = emb[Z[j] * kF + lane];
        #pragma unroll
        for (int q = 0; q < CG.n; q++) {
          if (CG.a[q] == 0) y[CG.c[q]] += CG.v[q] * YW[CG.b[q]] * e;
        }
      } else {
        const float* xj = x_in + j * kXs + lane * kCp;
        float xv[12];
        *(float4*)&xv[0] = *(const float4*)(xj + 0);
        *(float4*)&xv[4] = *(const float4*)(xj + 4);
        *(float4*)&xv[8] = *(const float4*)(xj + 8);
        #pragma unroll
        for (int q = 0; q < CG.n; q++) {
          y[CG.c[q]] += CG.v[q] * YW[CG.b[q]] * xv[CG.a[q]];
        }
      }
    }
    st12(sR[wv], lane, y);
  }
  __syncthreads();  // B1

  // ---- every wave: dxv = sum partials; sA = dx; mm1 -> sR[wv] ----
  float dxv[12];
  sum4(sR, lane, dxv);
  st12(sA, lane, dxv);      // own wave wrote all 64 rows -> no barrier
  mm_phase(sA, W1, sR[wv], k0, cgi, fb);
  __syncthreads();  // B2

  // ---- every wave: ddx = sum partials; t2 = dx + CG(dx,ddx); sA = t2 ----
  {
    float ddx[12];
    sum4(sR, lane, ddx);
    float t2[12];
    #pragma unroll
    for (int c = 0; c < 9; c++) t2[c] = dxv[c];
    t2[9] = 0.f; t2[10] = 0.f; t2[11] = 0.f;
    #pragma unroll
    for (int q = 0; q < CG.n; q++) {
      t2[CG.c[q]] += CG.v[q] * dxv[CG.a[q]] * ddx[CG.b[q]];
    }
    st12(sA, lane, t2);
  }
  mm_phase(sA, W2, sR[wv], k0, cgi, fb);
  __syncthreads();  // B3

  // ---- every wave: dx2 = sum partials; sA = dx2; full gate; dx3 -> sB ----
  {
    float dx2v[12];
    sum4(sR, lane, dx2v);
    st12(sA, lane, dx2v);   // gate reads own-wave-written rows
    float g0 = bg[lane], g1 = bg[64 + lane], g2 = bg[128 + lane];
    #pragma unroll 4
    for (int k = 0; k < kF; k++) {
      float a = sA[k * kCp];          // dx2[c=0][k], broadcast
      g0 += a * Wg[k * 192 + lane];
      g1 += a * Wg[k * 192 + 64 + lane];
      g2 += a * Wg[k * 192 + 128 + lane];
    }
    g0 = 1.f / (1.f + expf(-g0));
    g1 = 1.f / (1.f + expf(-g1));
    g2 = 1.f / (1.f + expf(-g2));
    float dx3[12];
    dx3[0] = dx2v[0] * g0;
    dx3[1] = dx2v[1] * g1;
    dx3[2] = dx2v[2] * g1;
    dx3[3] = dx2v[3] * g1;
    #pragma unroll
    for (int c = 4; c < 9; c++) dx3[c] = dx2v[c] * g2;
    dx3[9] = 0.f; dx3[10] = 0.f; dx3[11] = 0.f;
    st12(sB, lane, dx3);    // separate buffer: no race with gate's sA reads
  }
  mm_phase(sB, W3, sR[wv], k0, cgi, fb);
  __syncthreads();  // B4

  // ---- residual output ----
  if (T == 0) {
    // residual = x0 = emb[Z[atom]] in channel 0 only; out internal [f][12]
    if (tid < 192) {
      const int f = tid / 3, r = tid % 3;
      const float4* r0 = (const float4*)sR[0];
      const float4* r1 = (const float4*)sR[1];
      const float4* r2 = (const float4*)sR[2];
      const float4* r3 = (const float4*)sR[3];
      float4 a = r0[tid], b = r1[tid], c = r2[tid], d = r3[tid];
      float4 s = {a.x + b.x + c.x + d.x, a.y + b.y + c.y + d.y,
                  a.z + b.z + c.z + d.z, a.w + b.w + c.w + d.w};
      if (r == 0) s.x += emb[Z[atom] * kF + f];
      *(float4*)(x_out + atom * kXs + tid * 4) = s;
    }
  } else {
    // sum + residual (f-major, b128) -> sA, then c-major store
    if (tid < 192) {
      const float4* r0 = (const float4*)sR[0];
      const float4* r1 = (const float4*)sR[1];
      const float4* r2 = (const float4*)sR[2];
      const float4* r3 = (const float4*)sR[3];
      float4 a = r0[tid], b = r1[tid], c = r2[tid], d = r3[tid];
      float4 xi = *(const float4*)(x_in + atom * kXs + tid * 4);
      float4 s = {a.x + b.x + c.x + d.x + xi.x, a.y + b.y + c.y + d.y + xi.y,
                  a.z + b.z + c.z + d.z + xi.z, a.w + b.w + c.w + d.w + xi.w};
      ((float4*)sA)[tid] = s;
    }
    __syncthreads();  // B5 (T==1 only)
    #pragma unroll
    for (int r = 0; r < 3; r++) {
      int i = r * 256 + tid;        // 0..767, only < 576 valid
      if (i < kNsh * kF) {
        int c = i >> 6, f = i & 63;
        x_out[atom * (kNsh * kF) + i] = sA[f * kCp + c];
      }
    }
  }
}

// ---------------------------------------------------------------------------
// Launch: 3 dispatches (kernel boundaries provide all coherence)
// ---------------------------------------------------------------------------
extern "C" void kernel_launch(void* const* d_in, const int* in_sizes, int n_in,
                              void* d_out, int out_size, void* d_ws, size_t ws_size,
                              hipStream_t stream) {
  const int* Z        = (const int*)d_in[0];
  const float* rij    = (const float*)d_in[1];
  const int* idx_i    = (const int*)d_in[2];
  const int* idx_j    = (const int*)d_in[3];
  const float* emb    = (const float*)d_in[4];
  const float* Wf     = (const float*)d_in[5];
  const float* bf     = (const float*)d_in[6];
  const float* W1     = (const float*)d_in[7];
  const float* W2     = (const float*)d_in[8];
  const float* W3     = (const float*)d_in[9];
  const float* Wg     = (const float*)d_in[10];
  const float* bg     = (const float*)d_in[11];
  float* out = (float*)d_out;

  float* x1    = (float*)d_ws;                       // 768,000
  float* Ypd   = x1 + kNAtoms * kXs;                 // 160,000
  float* Wpair = Ypd + kNPairs * 16;                 // 3,840,000
  int*   seg   = (int*)(Wpair + 2 * kNPairs * 192);  // 1001

  k_pre<<<kPreBlkTotal, 256, 0, stream>>>(rij, Wf, bf, idx_i, Ypd, Wpair, seg);

  // t = 0: emb-gather -> x1 (internal layout)
  k_inter<0><<<kNAtoms, 256, 0, stream>>>(
      Ypd, Wpair, seg, idx_j, Z, emb, x1,
      W1, W2, W3, Wg, bg, x1);

  // t = 1: x1-gather -> d_out (standard layout)
  k_inter<1><<<kNAtoms, 256, 0, stream>>>(
      Ypd, Wpair + kNPairs * 192, seg, idx_j, Z, emb, x1,
      W1 + kF * kF, W2 + kF * kF, W3 + kF * kF,
      Wg + kF * 192, bg + 192, out);
}

// Round 15
// 122.999 us; speedup vs baseline: 1.1547x; 1.1547x over previous
//
#include <hip/hip_runtime.h>
#include <cmath>

// ---------------------------------------------------------------------------
// Problem constants (from reference)
// ---------------------------------------------------------------------------
constexpr int kNsh    = 9;      // (LMAX+1)^2, LMAX=2
constexpr int kF      = 64;
constexpr int kNrbf   = 20;
constexpr int kNAtoms = 1000;
constexpr int kNPairs = 10000;
constexpr float kCutoffF = 5.0f;
constexpr int kMaxNZ  = 200;
constexpr int kCp     = 12;         // channel dim padded (9 -> 12) for b128
constexpr int kXs     = kF * kCp;   // 768 floats per atom, internal layout

// ---------------------------------------------------------------------------
// Compile-time real Clebsch-Gordan table (mirrors the reference _real_cg)
// ---------------------------------------------------------------------------
struct CGSparse {
  int n;
  int c[kMaxNZ];
  int a[kMaxNZ];
  int b[kMaxNZ];
  float v[kMaxNZ];
};

constexpr double cfact(int n) {
  double r = 1.0;
  for (int i = 2; i <= n; i++) r *= (double)i;
  return r;
}
constexpr double cabs_(double x) { return x < 0 ? -x : x; }
constexpr double csqrt_(double x) {
  if (x <= 0.0) return 0.0;
  double g = x < 1.0 ? 1.0 : x;
  for (int i = 0; i < 60; i++) g = 0.5 * (g + x / g);
  return g;
}

constexpr double cg_cplx(int l1, int m1, int l2, int m2, int l3, int m3) {
  if (m3 != m1 + m2) return 0.0;
  int lo = l1 > l2 ? l1 - l2 : l2 - l1;
  if (l3 < lo || l3 > l1 + l2) return 0.0;
  double pre = csqrt_((2 * l3 + 1) * cfact(l3 + l1 - l2) * cfact(l3 - l1 + l2) *
                      cfact(l1 + l2 - l3) / cfact(l1 + l2 + l3 + 1));
  pre *= csqrt_(cfact(l3 + m3) * cfact(l3 - m3) * cfact(l1 - m1) *
                cfact(l1 + m1) * cfact(l2 - m2) * cfact(l2 + m2));
  double s = 0.0;
  for (int k = 0; k <= l1 + l2 - l3; k++) {
    int d0 = k, d1 = l1 + l2 - l3 - k, d2 = l1 - m1 - k;
    int d3 = l2 + m2 - k, d4 = l3 - l2 + m1 + k, d5 = l3 - l1 - m2 + k;
    if (d0 < 0 || d1 < 0 || d2 < 0 || d3 < 0 || d4 < 0 || d5 < 0) continue;
    double den = cfact(d0) * cfact(d1) * cfact(d2) * cfact(d3) * cfact(d4) * cfact(d5);
    s += ((k % 2) ? -1.0 : 1.0) / den;
  }
  return pre * s;
}

constexpr CGSparse build_cg() {
  CGSparse out{};
  int lidx[9] = {0, 1, 1, 1, 2, 2, 2, 2, 2};
  int midx[9] = {0, -1, 0, 1, -2, -1, 0, 1, 2};
  double Ur[9][9] = {};
  double Ui[9][9] = {};
  for (int l = 0; l <= 2; l++) {
    int base = l * l + l;
    Ur[base][base] = 1.0;
    for (int m = 1; m <= l; m++) {
      double s2 = 1.0 / csqrt_(2.0);
      double sgn = (m % 2) ? -1.0 : 1.0;
      Ur[base + m][base - m] = s2;
      Ur[base + m][base + m] = sgn * s2;
      Ui[base - m][base - m] = s2;
      Ui[base - m][base + m] = -sgn * s2;
    }
  }
  double cgr[9][9][9] = {};
  for (int i = 0; i < 9; i++)
    for (int j = 0; j < 9; j++)
      for (int k = 0; k < 9; k++) {
        double cv = cg_cplx(lidx[i], midx[i], lidx[j], midx[j], lidx[k], midx[k]);
        if (cv == 0.0) continue;
        for (int a2 = 0; a2 < 9; a2++) {
          if (Ur[a2][i] == 0.0 && Ui[a2][i] == 0.0) continue;
          for (int b2 = 0; b2 < 9; b2++) {
            if (Ur[b2][j] == 0.0 && Ui[b2][j] == 0.0) continue;
            for (int c2 = 0; c2 < 9; c2++) {
              if (Ur[c2][k] == 0.0 && Ui[c2][k] == 0.0) continue;
              double ar = Ur[a2][i], ai = Ui[a2][i];
              double br = Ur[b2][j], bi = Ui[b2][j];
              double cr = Ur[c2][k], ci = -Ui[c2][k];  // conj
              double pr = ar * br - ai * bi;
              double pi = ar * bi + ai * br;
              double rr = pr * cr - pi * ci;  // real part
              cgr[c2][a2][b2] += rr * cv;
            }
          }
        }
      }
  int n = 0;
  for (int c2 = 0; c2 < 9; c2++)
    for (int a2 = 0; a2 < 9; a2++)
      for (int b2 = 0; b2 < 9; b2++) {
        bool mask = ((lidx[a2] + lidx[b2]) % 2) == (lidx[c2] % 2);
        double v = mask ? cgr[c2][a2][b2] : 0.0;
        if (cabs_(v) > 1e-9) {
          out.c[n] = c2;
          out.a[n] = a2;
          out.b[n] = b2;
          out.v[n] = (float)v;
          n++;
        }
      }
  out.n = n;
  return out;
}

constexpr CGSparse CG = build_cg();
static_assert(CG.n > 0 && CG.n <= kMaxNZ, "CG table size out of range");

// ---------------------------------------------------------------------------
// k_pre: compact per-pair record pd[32]: Y[0..8], cut[9], radial*cut[10..29]
// (one expf per lane; no Wf traffic). | segment offsets.
// ---------------------------------------------------------------------------
constexpr int kPreBlkPairs = kNPairs / 4;                 // 2500
constexpr int kPreBlkSeg   = (kNAtoms + 1 + 255) / 256;   // 4
constexpr int kPreBlkTotal = kPreBlkPairs + kPreBlkSeg;

__global__ __launch_bounds__(256) void k_pre(
    const float* __restrict__ rij, const int* __restrict__ idx_i,
    float* __restrict__ pd_all, int* __restrict__ seg) {
  const int blk = blockIdx.x;
  if (blk < kPreBlkPairs) {
    int wv = threadIdx.x >> 6;
    int f = threadIdx.x & 63;
    int p = blk * 4 + wv;
    float rx = rij[3 * p + 0], ry = rij[3 * p + 1], rz = rij[3 * p + 2];
    float d = sqrtf(rx * rx + ry * ry + rz * rz);
    float inv = 1.0f / d;
    float x = rx * inv, y = ry * inv, z = rz * inv;
    const float c0 = 0.28209479177387814f;  // 0.5/sqrt(pi)
    const float c1 = 0.4886025119029199f;   // sqrt(3/(4pi))
    const float c2 = 1.0925484305920792f;   // 0.5*sqrt(15/pi)
    const float c3 = 0.31539156525252005f;  // 0.25*sqrt(5/pi)
    const float c4 = 0.5462742152960396f;   // 0.25*sqrt(15/pi)
    float cut = (d < kCutoffF) ? 0.5f * (cosf(d * (float)(M_PI / 5.0)) + 1.0f) : 0.0f;
    float val = 0.f;
    if (f < 9) {
      val =
          (f == 0) ? c0 :
          (f == 1) ? c1 * y :
          (f == 2) ? c1 * z :
          (f == 3) ? c1 * x :
          (f == 4) ? c2 * x * y :
          (f == 5) ? c2 * y * z :
          (f == 6) ? c3 * (3.0f * z * z - 1.0f) :
          (f == 7) ? c2 * x * z :
                     c4 * (x * x - y * y);
    } else if (f == 9) {
      val = cut;
    } else if (f < 30) {
      const float width = kCutoffF / (kNrbf - 1);
      const float coef = -0.5f / (width * width);
      float off = (kCutoffF * (f - 10)) / (kNrbf - 1);
      float tt = d - off;
      val = expf(coef * tt * tt) * cut;   // radial*cut (bias term uses cut)
    }
    if (f < 30) pd_all[p * 32 + f] = val;
  } else {
    int a = (blk - kPreBlkPairs) * 256 + threadIdx.x;
    if (a <= kNAtoms) {
      int lo = 0, hi = kNPairs;
      while (lo < hi) {
        int mid = (lo + hi) >> 1;
        if (idx_i[mid] < a) lo = mid + 1; else hi = mid;
      }
      seg[a] = lo;
    }
  }
}

// ---------------------------------------------------------------------------
// Helpers
// ---------------------------------------------------------------------------
// k-split matmul partial: wave covers 16 k-slices of the 12c x 64f tile.
// W streamed from global (L2-broadcast) in two 8-slice register stages.
__device__ __forceinline__ void mm_phase(const float* __restrict__ sIn,
                                         const float* __restrict__ W,
                                         float* __restrict__ sRw,
                                         int k0, int cgi, int fb) {
  if (cgi >= 3) return;
  const int c0 = cgi * 4;
  float acc[4][4];
  #pragma unroll
  for (int i = 0; i < 4; i++)
    #pragma unroll
    for (int j = 0; j < 4; j++) acc[i][j] = 0.f;
  #pragma unroll
  for (int half = 0; half < 2; half++) {
    float4 wr[8];
    #pragma unroll
    for (int kk = 0; kk < 8; kk++) {
      wr[kk] = *(const float4*)(W + (k0 + half * 8 + kk) * kF + fb);
    }
    #pragma unroll
    for (int kk = 0; kk < 8; kk++) {
      int k = k0 + half * 8 + kk;
      float4 av = *(const float4*)(sIn + k * kCp + c0);
      float4 wv = wr[kk];
      float a[4] = {av.x, av.y, av.z, av.w};
      float w[4] = {wv.x, wv.y, wv.z, wv.w};
      #pragma unroll
      for (int i = 0; i < 4; i++)
        #pragma unroll
        for (int j = 0; j < 4; j++) acc[i][j] += a[i] * w[j];
    }
  }
  #pragma unroll
  for (int j = 0; j < 4; j++) {
    float4 v = {acc[0][j], acc[1][j], acc[2][j], acc[3][j]};
    *(float4*)(sRw + (fb + j) * kCp + c0) = v;
  }
}

// ---------------------------------------------------------------------------
// k_inter<T>: fused message + update, one block (4 waves) per atom.
// Filters reconstructed on the fly: W_l[f] = bf_l[f]*cut + sum_k radcut[k] *
// Wf[k][l*64+f], with Wf staged in LDS (15 KB, L2-broadcast across blocks).
// T==0: gather emb[Z[j]] (x0 virtual), write internal [f][12].
// T==1: gather x1, write standard [c][f] to out.
// ---------------------------------------------------------------------------
template <int T>
__global__ __launch_bounds__(256) void k_inter(
    const float* __restrict__ pd_all, const float* __restrict__ Wft,
    const float* __restrict__ bft, const int* __restrict__ seg,
    const int* __restrict__ idx_j, const int* __restrict__ Z,
    const float* __restrict__ emb, const float* __restrict__ x_in,
    const float* __restrict__ W1, const float* __restrict__ W2,
    const float* __restrict__ W3, const float* __restrict__ Wg,
    const float* __restrict__ bg, float* __restrict__ x_out) {
  const int atom = blockIdx.x;
  const int tid = threadIdx.x;
  const int wv = tid >> 6;          // wave 0..3
  const int lane = tid & 63;
  const int cgi = lane >> 4;        // 0..3 (3 idle in mm)
  const int fb = (lane & 15) * 4;
  const int k0 = wv * 16;           // k-range for this wave

  __shared__ __align__(16) float sWf[kNrbf * 192];  // 15 KB radial filters
  __shared__ __align__(16) float sA[kF * kCp];      // 3 KB staging, f-major
  __shared__ __align__(16) float sR[4][kF * kCp];   // 12 KB per-wave partials
  __shared__ __align__(16) float sGp[4][192];       // 3 KB gate partials

  // ---- stage Wf into LDS (960 float4s, coalesced, L2-broadcast) ----
  {
    const float4* g4 = (const float4*)Wft;
    float4* s4 = (float4*)sWf;
    #pragma unroll
    for (int r = 0; r < 4; r++) {
      int i = r * 256 + tid;
      if (i < kNrbf * 192 / 4) s4[i] = g4[i];
    }
  }
  const float bf0 = bft[lane], bf1 = bft[64 + lane], bf2 = bft[128 + lane];
  __syncthreads();  // B0

  // ---- message + aggregation (pairs split across 4 waves) ----
  {
    float y[12];
    #pragma unroll
    for (int c = 0; c < 12; c++) y[c] = 0.f;
    const int s0 = seg[atom], s1 = seg[atom + 1];
    for (int p0 = s0 + wv; p0 < s1; p0 += 4) {
      const int p = __builtin_amdgcn_readfirstlane(p0);
      const int j = __builtin_amdgcn_readfirstlane(idx_j[p]);
      const float* pd = pd_all + p * 32;
      const float cut = pd[9];
      // reconstruct per-pair filters from pd + LDS Wf
      float Wl0 = bf0 * cut, Wl1 = bf1 * cut, Wl2 = bf2 * cut;
      #pragma unroll
      for (int k = 0; k < kNrbf; k++) {
        float r = pd[10 + k];               // pair-uniform broadcast
        Wl0 += r * sWf[k * 192 + lane];
        Wl1 += r * sWf[k * 192 + 64 + lane];
        Wl2 += r * sWf[k * 192 + 128 + lane];
      }
      float YW[9];
      YW[0] = pd[0] * Wl0;
      YW[1] = pd[1] * Wl1;
      YW[2] = pd[2] * Wl1;
      YW[3] = pd[3] * Wl1;
      #pragma unroll
      for (int b = 4; b < 9; b++) YW[b] = pd[b] * Wl2;
      if (T == 0) {
        // x[j] = emb[Z[j]] in channel 0 only: CG folds to a==0 entries
        float e = emb[Z[j] * kF + lane];
        #pragma unroll
        for (int q = 0; q < CG.n; q++) {
          if (CG.a[q] == 0) y[CG.c[q]] += CG.v[q] * YW[CG.b[q]] * e;
        }
      } else {
        const float* xj = x_in + j * kXs + lane * kCp;
        float xv[12];
        *(float4*)&xv[0] = *(const float4*)(xj + 0);
        *(float4*)&xv[4] = *(const float4*)(xj + 4);
        *(float4*)&xv[8] = *(const float4*)(xj + 8);
        #pragma unroll
        for (int q = 0; q < CG.n; q++) {
          y[CG.c[q]] += CG.v[q] * YW[CG.b[q]] * xv[CG.a[q]];
        }
      }
    }
    float4* r4 = (float4*)(sR[wv] + lane * kCp);
    r4[0] = *(float4*)&y[0];
    r4[1] = *(float4*)&y[4];
    r4[2] = *(float4*)&y[8];
  }
  __syncthreads();  // B1
  // reduce partials -> sA (dx, f-major); float4 granularity
  if (tid < 192) {
    const float4* r0 = (const float4*)sR[0];
    const float4* r1 = (const float4*)sR[1];
    const float4* r2 = (const float4*)sR[2];
    const float4* r3 = (const float4*)sR[3];
    float4 a = r0[tid], b = r1[tid], c = r2[tid], d = r3[tid];
    float4 s = {a.x + b.x + c.x + d.x, a.y + b.y + c.y + d.y,
                a.z + b.z + c.z + d.z, a.w + b.w + c.w + d.w};
    ((float4*)sA)[tid] = s;
  }
  __syncthreads();  // B2

  // ---- matmul1: ddx = dx @ W1 (k-split, streamed reg W) ----
  mm_phase(sA, W1, sR[wv], k0, cgi, fb);
  __syncthreads();  // B3

  // ---- wave0: tp (t2 = dx + CG(dx, ddx)) ----
  if (wv == 0) {
    float dxv[12], ddx[12];
    {
      const float4* sa = (const float4*)(sA + lane * kCp);
      *(float4*)&dxv[0] = sa[0];
      *(float4*)&dxv[4] = sa[1];
      *(float4*)&dxv[8] = sa[2];
    }
    #pragma unroll
    for (int c = 0; c < 12; c++) {
      ddx[c] = sR[0][lane * kCp + c] + sR[1][lane * kCp + c] +
               sR[2][lane * kCp + c] + sR[3][lane * kCp + c];
    }
    float t2[12];
    #pragma unroll
    for (int c = 0; c < 9; c++) t2[c] = dxv[c];
    t2[9] = 0.f; t2[10] = 0.f; t2[11] = 0.f;
    #pragma unroll
    for (int q = 0; q < CG.n; q++) {
      t2[CG.c[q]] += CG.v[q] * dxv[CG.a[q]] * ddx[CG.b[q]];
    }
    float4* sa = (float4*)(sA + lane * kCp);
    sa[0] = *(float4*)&t2[0];
    sa[1] = *(float4*)&t2[4];
    sa[2] = *(float4*)&t2[8];
  }
  __syncthreads();  // B4

  // ---- matmul2: dx2 = t2 @ W2 (k-split, streamed reg W) ----
  mm_phase(sA, W2, sR[wv], k0, cgi, fb);
  __syncthreads();  // B5

  // ---- gate partials (k-split) ----
  {
    float g0 = 0.f, g1 = 0.f, g2 = 0.f;
    #pragma unroll 4
    for (int kk = 0; kk < 16; kk++) {
      int k = k0 + kk;
      float a = sR[0][k * kCp] + sR[1][k * kCp] + sR[2][k * kCp] + sR[3][k * kCp];
      g0 += a * Wg[k * 192 + lane];
      g1 += a * Wg[k * 192 + 64 + lane];
      g2 += a * Wg[k * 192 + 128 + lane];
    }
    sGp[wv][lane] = g0;
    sGp[wv][64 + lane] = g1;
    sGp[wv][128 + lane] = g2;
  }
  __syncthreads();  // B6

  // ---- wave0: dx3 = dx2 * sigmoid(gate)[lidx] -> sA ----
  if (wv == 0) {
    float dx2v[12];
    #pragma unroll
    for (int c = 0; c < 12; c++) {
      dx2v[c] = sR[0][lane * kCp + c] + sR[1][lane * kCp + c] +
                sR[2][lane * kCp + c] + sR[3][lane * kCp + c];
    }
    float g0 = bg[lane] + sGp[0][lane] + sGp[1][lane] + sGp[2][lane] + sGp[3][lane];
    float g1 = bg[64 + lane] + sGp[0][64 + lane] + sGp[1][64 + lane] +
               sGp[2][64 + lane] + sGp[3][64 + lane];
    float g2 = bg[128 + lane] + sGp[0][128 + lane] + sGp[1][128 + lane] +
               sGp[2][128 + lane] + sGp[3][128 + lane];
    g0 = 1.f / (1.f + expf(-g0));
    g1 = 1.f / (1.f + expf(-g1));
    g2 = 1.f / (1.f + expf(-g2));
    float dx3[12];
    dx3[0] = dx2v[0] * g0;
    dx3[1] = dx2v[1] * g1;
    dx3[2] = dx2v[2] * g1;
    dx3[3] = dx2v[3] * g1;
    #pragma unroll
    for (int c = 4; c < 9; c++) dx3[c] = dx2v[c] * g2;
    dx3[9] = 0.f; dx3[10] = 0.f; dx3[11] = 0.f;
    float4* sa = (float4*)(sA + lane * kCp);
    sa[0] = *(float4*)&dx3[0];
    sa[1] = *(float4*)&dx3[4];
    sa[2] = *(float4*)&dx3[8];
  }
  __syncthreads();  // B7

  // ---- matmul3: out = dx3 @ W3 (k-split, streamed reg W) ----
  mm_phase(sA, W3, sR[wv], k0, cgi, fb);
  __syncthreads();  // B8

  // ---- residual output ----
  if (T == 0) {
    // residual = x0 = emb[Z[atom]] in channel 0 only; out internal [f][12]
    if (tid < 192) {
      const int f = tid / 3, r = tid % 3;
      const float4* r0 = (const float4*)sR[0];
      const float4* r1 = (const float4*)sR[1];
      const float4* r2 = (const float4*)sR[2];
      const float4* r3 = (const float4*)sR[3];
      float4 a = r0[tid], b = r1[tid], c = r2[tid], d = r3[tid];
      float4 s = {a.x + b.x + c.x + d.x, a.y + b.y + c.y + d.y,
                  a.z + b.z + c.z + d.z, a.w + b.w + c.w + d.w};
      if (r == 0) s.x += emb[Z[atom] * kF + f];
      *(float4*)(x_out + atom * kXs + tid * 4) = s;
    }
  } else {
    // sum + residual (f-major, b128) -> sA, then c-major store
    if (tid < 192) {
      const float4* r0 = (const float4*)sR[0];
      const float4* r1 = (const float4*)sR[1];
      const float4* r2 = (const float4*)sR[2];
      const float4* r3 = (const float4*)sR[3];
      float4 a = r0[tid], b = r1[tid], c = r2[tid], d = r3[tid];
      float4 xi = *(const float4*)(x_in + atom * kXs + tid * 4);
      float4 s = {a.x + b.x + c.x + d.x + xi.x, a.y + b.y + c.y + d.y + xi.y,
                  a.z + b.z + c.z + d.z + xi.z, a.w + b.w + c.w + d.w + xi.w};
      ((float4*)sA)[tid] = s;
    }
    __syncthreads();  // B9
    #pragma unroll
    for (int r = 0; r < 3; r++) {
      int i = r * 256 + tid;        // 0..767, only < 576 valid
      if (i < kNsh * kF) {
        int c = i >> 6, f = i & 63;
        x_out[atom * (kNsh * kF) + i] = sA[f * kCp + c];
      }
    }
  }
}

// ---------------------------------------------------------------------------
// Launch: 3 dispatches (kernel boundaries provide all coherence)
// ---------------------------------------------------------------------------
extern "C" void kernel_launch(void* const* d_in, const int* in_sizes, int n_in,
                              void* d_out, int out_size, void* d_ws, size_t ws_size,
                              hipStream_t stream) {
  const int* Z        = (const int*)d_in[0];
  const float* rij    = (const float*)d_in[1];
  const int* idx_i    = (const int*)d_in[2];
  const int* idx_j    = (const int*)d_in[3];
  const float* emb    = (const float*)d_in[4];
  const float* Wf     = (const float*)d_in[5];
  const float* bf     = (const float*)d_in[6];
  const float* W1     = (const float*)d_in[7];
  const float* W2     = (const float*)d_in[8];
  const float* W3     = (const float*)d_in[9];
  const float* Wg     = (const float*)d_in[10];
  const float* bg     = (const float*)d_in[11];
  float* out = (float*)d_out;

  float* x1  = (float*)d_ws;                   // 768,000 floats
  float* pd  = x1 + kNAtoms * kXs;             // 320,000 floats (10000 x 32)
  int*   seg = (int*)(pd + kNPairs * 32);      // 1001 ints

  k_pre<<<kPreBlkTotal, 256, 0, stream>>>(rij, idx_i, pd, seg);

  // t = 0: emb-gather -> x1 (internal layout)
  k_inter<0><<<kNAtoms, 256, 0, stream>>>(
      pd, Wf, bf, seg, idx_j, Z, emb, x1,
      W1, W2, W3, Wg, bg, x1);

  // t = 1: x1-gather -> d_out (standard layout)
  k_inter<1><<<kNAtoms, 256, 0, stream>>>(
      pd, Wf + kNrbf * 192, bf + 192, seg, idx_j, Z, emb, x1,
      W1 + kF * kF, W2 + kF * kF, W3 + kF * kF,
      Wg + kF * 192, bg + 192, out);
}